// Round 6
// baseline (206.983 us; speedup 1.0000x reference)
//
#include <hip/hip_runtime.h>

#define B_  8
#define N_  8192
#define S_  2048
#define C1_ 128
#define C2_ 256
#define KA_ 384   // C1_+C2_
#define H0_ 256
#define H1_ 128
#define R_  (B_ * N_)   // 65536

typedef __bf16 bf16;
typedef __attribute__((ext_vector_type(4))) __bf16 bf16x4;
typedef __attribute__((ext_vector_type(8))) __bf16 bf16x8;
typedef __attribute__((ext_vector_type(4))) float f32x4;

__device__ __forceinline__ void gload_lds16(const void* g, void* l) {
    __builtin_amdgcn_global_load_lds(
        (const __attribute__((address_space(1))) void*)g,
        (__attribute__((address_space(3))) void*)l, 16, 0, 0);
}

// branchless top-3 insert: 3 cmp + 10 cndmask (strict < keeps earliest index = stable)
__device__ __forceinline__ void ins3(float m, int s,
                                     float& m0, float& m1, float& m2,
                                     int& j0, int& j1, int& j2)
{
    bool b0 = m < m0, b1 = m < m1, b2 = m < m2;
    m2 = b1 ? m1 : (b2 ? m : m2);  j2 = b1 ? j1 : (b2 ? s : j2);
    m1 = b0 ? m0 : (b1 ? m : m1);  j1 = b0 ? j0 : (b1 ? s : j1);
    m0 = b0 ? m  : m0;             j0 = b0 ? s  : j0;
}

// ---------------- zero stats ----------------
__global__ void zero_kernel(float* __restrict__ p, int n) {
    int i = blockIdx.x * 256 + threadIdx.x;
    if (i < n) p[i] = 0.f;
}

// ---------------- f32 -> bf16 contiguous cast (weights) ----------------
__global__ __launch_bounds__(256) void cvt_kernel(const float* __restrict__ src,
                                                  bf16* __restrict__ dst, int n4) {
    int i = blockIdx.x * 256 + threadIdx.x;
    if (i < n4) {
        float4 v = *(const float4*)(src + (size_t)i * 4);
        bf16x4 o = { (bf16)v.x, (bf16)v.y, (bf16)v.z, (bf16)v.w };
        *(bf16x4*)(dst + (size_t)i * 4) = o;
    }
}

// ---------------- points1 f32 -> Abf cols [0,128) ----------------
__global__ __launch_bounds__(256) void p1cvt_kernel(const float* __restrict__ p1,
                                                    bf16* __restrict__ Abf) {
    int e = blockIdx.x * 256 + threadIdx.x;
    int row = e >> 5, kc = e & 31;
    float4 v = *(const float4*)(p1 + (size_t)row * C1_ + kc * 4);
    bf16x4 o = { (bf16)v.x, (bf16)v.y, (bf16)v.z, (bf16)v.w };
    *(bf16x4*)(Abf + (size_t)row * KA_ + kc * 4) = o;
}

// ---------------- top-3 NN v6: branchless, Q=2 queries/thread, split-8 ----------
// grid: B_ * (N_/64) = 1024 blocks, 256 threads = 32 qpairs x 8 splits.
// Thread (qp,sp) scans s = 8*i+sp (8 float4 addrs span all 32 banks) and updates
// top-3 for 2 queries branchlessly (16 VALU/visit). LDS reads halved vs Q=1.
__global__ __launch_bounds__(256) void top3_kernel(
    const float* __restrict__ xyz1, const float* __restrict__ xyz2,
    int* __restrict__ out_idx, float* __restrict__ out_w)
{
    __shared__ float4 sc[S_];          // 32 KB: (x,y,z,|c|^2)
    __shared__ float  md[64][8][3];    // 6 KB
    __shared__ int    mi[64][8][3];    // 6 KB

    int b = blockIdx.x >> 7;           // 128 tiles per batch
    int ntile = blockIdx.x & 127;
    const float* src = xyz2 + (size_t)b * S_ * 3;
    for (int i = threadIdx.x; i < S_; i += 256) {
        float x = src[i * 3 + 0], y = src[i * 3 + 1], z = src[i * 3 + 2];
        float4 c; c.x = x; c.y = y; c.z = z; c.w = x * x + y * y + z * z;
        sc[i] = c;
    }
    __syncthreads();

    const int qp = threadIdx.x >> 3;   // [0,32) -> queries 2qp, 2qp+1
    const int sp = threadIdx.x & 7;    // [0,8)
    const size_t rowA = (size_t)b * N_ + ntile * 64 + qp * 2;
    const float axA = -2.f * xyz1[rowA * 3 + 0];
    const float ayA = -2.f * xyz1[rowA * 3 + 1];
    const float azA = -2.f * xyz1[rowA * 3 + 2];
    const float axB = -2.f * xyz1[rowA * 3 + 3];
    const float ayB = -2.f * xyz1[rowA * 3 + 4];
    const float azB = -2.f * xyz1[rowA * 3 + 5];

    float a0 = 1e30f, a1 = 1e30f, a2 = 1e30f;
    float e0 = 1e30f, e1 = 1e30f, e2 = 1e30f;
    int   u0 = 0, u1 = 0, u2 = 0, v0 = 0, v1 = 0, v2 = 0;

    #pragma unroll 4
    for (int i = 0; i < S_ / 8; ++i) {
        int s = i * 8 + sp;
        float4 c = sc[s];
        float mA = fmaf(axA, c.x, fmaf(ayA, c.y, fmaf(azA, c.z, c.w)));
        float mB = fmaf(axB, c.x, fmaf(ayB, c.y, fmaf(azB, c.z, c.w)));
        ins3(mA, s, a0, a1, a2, u0, u1, u2);
        ins3(mB, s, e0, e1, e2, v0, v1, v2);
    }
    int qa = qp * 2, qb = qa + 1;
    md[qa][sp][0] = a0; md[qa][sp][1] = a1; md[qa][sp][2] = a2;
    mi[qa][sp][0] = u0; mi[qa][sp][1] = u1; mi[qa][sp][2] = u2;
    md[qb][sp][0] = e0; md[qb][sp][1] = e1; md[qb][sp][2] = e2;
    mi[qb][sp][0] = v0; mi[qb][sp][1] = v1; mi[qb][sp][2] = v2;
    __syncthreads();

    if (threadIdx.x < 64) {
        int qq = threadIdx.x;
        float d0 = md[qq][0][0], d1 = md[qq][0][1], d2 = md[qq][0][2];
        int   i0 = mi[qq][0][0], i1 = mi[qq][0][1], i2 = mi[qq][0][2];
        #pragma unroll
        for (int p = 1; p < 8; ++p) {
            #pragma unroll
            for (int j = 0; j < 3; ++j) {
                float d = md[qq][p][j]; int s = mi[qq][p][j];
                bool lt2 = (d < d2) || (d == d2 && s < i2);
                if (lt2) {
                    bool lt1 = (d < d1) || (d == d1 && s < i1);
                    if (lt1) {
                        d2 = d1; i2 = i1;
                        bool lt0 = (d < d0) || (d == d0 && s < i0);
                        if (lt0) { d1 = d0; i1 = i0; d0 = d; i0 = s; }
                        else     { d1 = d;  i1 = s; }
                    } else { d2 = d; i2 = s; }
                }
            }
        }
        size_t orow = (size_t)b * N_ + ntile * 64 + qq;
        float px = xyz1[orow * 3 + 0], py = xyz1[orow * 3 + 1], pz = xyz1[orow * 3 + 2];
        float pp = px * px + py * py + pz * pz;
        float r0 = 1.f / (d0 + pp + 1e-8f);
        float r1 = 1.f / (d1 + pp + 1e-8f);
        float r2 = 1.f / (d2 + pp + 1e-8f);
        float inv = 1.f / (r0 + r1 + r2);
        out_idx[orow * 3 + 0] = i0; out_idx[orow * 3 + 1] = i1; out_idx[orow * 3 + 2] = i2;
        out_w[orow * 3 + 0] = r0 * inv; out_w[orow * 3 + 1] = r1 * inv; out_w[orow * 3 + 2] = r2 * inv;
    }
}

// ---------------- gather + interp -> Abf cols [128,384) as bf16 ----------------
__global__ __launch_bounds__(256) void interp_kernel(
    const float* __restrict__ points2, const int* __restrict__ idx3,
    const float* __restrict__ w3, bf16* __restrict__ Abf)
{
    int t = threadIdx.x;
    size_t row = (size_t)blockIdx.x * 4 + (t >> 6);
    int lane = t & 63;
    int b = (int)(row >> 13);
    const float* p2 = points2 + (size_t)b * S_ * C2_;
    int ia = idx3[row * 3 + 0], ib = idx3[row * 3 + 1], ic = idx3[row * 3 + 2];
    float wa = w3[row * 3 + 0], wb = w3[row * 3 + 1], wc = w3[row * 3 + 2];
    float4 va = *(const float4*)(p2 + (size_t)ia * C2_ + lane * 4);
    float4 vb = *(const float4*)(p2 + (size_t)ib * C2_ + lane * 4);
    float4 vc = *(const float4*)(p2 + (size_t)ic * C2_ + lane * 4);
    bf16x4 o = { (bf16)(wa * va.x + wb * vb.x + wc * vc.x),
                 (bf16)(wa * va.y + wb * vb.y + wc * vc.y),
                 (bf16)(wa * va.z + wb * vb.z + wc * vc.z),
                 (bf16)(wa * va.w + wb * vb.w + wc * vc.w) };
    *(bf16x4*)(Abf + row * KA_ + C1_ + lane * 4) = o;
}

// ---------------- MFMA bf16 GEMM with fused BN-stats epilogue -------------------
// C[r][o] = sum_k A[r][k]*Wt[o][k]; per-column sums/sumsq accumulated via
// LDS reduce + global atomics (saves a full stats pass over the output).
template<int K, int OT, bool OUTBF>
__global__ __launch_bounds__(256) void mfma_gemm_kernel(
    const bf16* __restrict__ A, const bf16* __restrict__ Wt, void* __restrict__ Cout,
    float* __restrict__ sums, float* __restrict__ sumsq)
{
    __shared__ bf16 As[128 * 32];
    __shared__ bf16 Bs[128 * 32];
    __shared__ float csum[128], csumsq[128];
    const int tid = threadIdx.x;
    const int lane = tid & 63, wave = tid >> 6;
    const int wr = wave >> 1, wc = wave & 1;
    const int r0 = blockIdx.x * 128, o0 = blockIdx.y * 128;

    f32x4 acc[4][4] = {};

    const int l15 = lane & 15, g = lane >> 4;
    const int slot = g ^ ((l15 >> 1) & 3);
    int a_off[4], b_off[4];
    #pragma unroll
    for (int m = 0; m < 4; ++m) a_off[m] = (wr * 64 + m * 16 + l15) * 32 + slot * 8;
    #pragma unroll
    for (int n = 0; n < 4; ++n) b_off[n] = (wc * 64 + n * 16 + l15) * 32 + slot * 8;

    const int c0 = tid, c1 = tid + 256;
    const int ar0 = c0 >> 2, ar1 = c1 >> 2;
    const int kb0 = ((c0 & 3) ^ ((ar0 >> 1) & 3)) * 8;
    const int kb1 = ((c1 & 3) ^ ((ar1 >> 1) & 3)) * 8;

    if (tid < 128) { csum[tid] = 0.f; csumsq[tid] = 0.f; }

    for (int k0 = 0; k0 < K; k0 += 32) {
        __syncthreads();
        gload_lds16(A  + (size_t)(r0 + ar0) * K + k0 + kb0, &As[c0 * 8]);
        gload_lds16(A  + (size_t)(r0 + ar1) * K + k0 + kb1, &As[c1 * 8]);
        gload_lds16(Wt + (size_t)(o0 + ar0) * K + k0 + kb0, &Bs[c0 * 8]);
        gload_lds16(Wt + (size_t)(o0 + ar1) * K + k0 + kb1, &Bs[c1 * 8]);
        __syncthreads();
        bf16x8 af[4], bfr[4];
        #pragma unroll
        for (int m = 0; m < 4; ++m) af[m]  = *(const bf16x8*)&As[a_off[m]];
        #pragma unroll
        for (int n = 0; n < 4; ++n) bfr[n] = *(const bf16x8*)&Bs[b_off[n]];
        #pragma unroll
        for (int m = 0; m < 4; ++m)
            #pragma unroll
            for (int n = 0; n < 4; ++n)
                acc[m][n] = __builtin_amdgcn_mfma_f32_16x16x32_bf16(af[m], bfr[n], acc[m][n], 0, 0, 0);
    }

    const int crow = r0 + wr * 64 + g * 4;
    const int ccol = o0 + wc * 64 + l15;
    #pragma unroll
    for (int m = 0; m < 4; ++m)
        #pragma unroll
        for (int n = 0; n < 4; ++n)
            #pragma unroll
            for (int j = 0; j < 4; ++j) {
                size_t off = (size_t)(crow + m * 16 + j) * OT + ccol + n * 16;
                if (OUTBF) ((bf16*)Cout)[off] = (bf16)acc[m][n][j];
                else       ((float*)Cout)[off] = acc[m][n][j];
            }

    // fused BN-stats: per-column partials from registers -> LDS -> global atomics
    #pragma unroll
    for (int n = 0; n < 4; ++n) {
        float s = 0.f, q = 0.f;
        #pragma unroll
        for (int m = 0; m < 4; ++m)
            #pragma unroll
            for (int j = 0; j < 4; ++j) {
                float v = acc[m][n][j];
                s += v; q = fmaf(v, v, q);
            }
        int col = wc * 64 + n * 16 + l15;
        atomicAdd(&csum[col], s);
        atomicAdd(&csumsq[col], q);
    }
    __syncthreads();
    if (tid < 128) {
        atomicAdd(&sums[o0 + tid], csum[tid]);
        atomicAdd(&sumsq[o0 + tid], csumsq[tid]);
    }
}

__global__ void finalize_kernel(const float* __restrict__ sums, const float* __restrict__ sumsq,
                                const float* __restrict__ g, const float* __restrict__ be,
                                float* __restrict__ scale, float* __restrict__ shift, float invR)
{
    int c = threadIdx.x;
    float mean = sums[c] * invR;
    float var = sumsq[c] * invR - mean * mean;
    float s = g[c] * rsqrtf(var + 1e-5f);
    scale[c] = s;
    shift[c] = be[c] - mean * s;
}

// ---------------- BN+ReLU on bf16 h -> bf16 (feeds GEMM2) ----------------
__global__ __launch_bounds__(256) void bnrelu_cvt_kernel(const bf16* __restrict__ hp,
                                                         const float* __restrict__ scale,
                                                         const float* __restrict__ shift,
                                                         bf16* __restrict__ hb)
{
    size_t i8 = (size_t)blockIdx.x * 256 + threadIdx.x;
    int c0 = (int)((i8 * 8) & (H0_ - 1));
    bf16x8 v = *(const bf16x8*)(hp + i8 * 8);
    bf16x8 o;
    #pragma unroll
    for (int j = 0; j < 8; ++j) {
        float f = (float)v[j];
        f = fmaxf(0.f, f * scale[c0 + j] + shift[c0 + j]);
        o[j] = (bf16)f;
    }
    *(bf16x8*)(hb + i8 * 8) = o;
}

// ---------------- final in-place BN+ReLU on d_out (f32) ----------------
__global__ __launch_bounds__(256) void bnrelu_kernel(float* __restrict__ X,
                                                     const float* __restrict__ scale,
                                                     const float* __restrict__ shift)
{
    size_t i = (size_t)blockIdx.x * 256 + threadIdx.x;
    float4 v = *(float4*)(X + i * 4);
    int c = (int)((i * 4) & (H1_ - 1));
    v.x = fmaxf(0.f, v.x * scale[c + 0] + shift[c + 0]);
    v.y = fmaxf(0.f, v.y * scale[c + 1] + shift[c + 1]);
    v.z = fmaxf(0.f, v.z * scale[c + 2] + shift[c + 2]);
    v.w = fmaxf(0.f, v.w * scale[c + 3] + shift[c + 3]);
    *(float4*)(X + i * 4) = v;
}

extern "C" void kernel_launch(void* const* d_in, const int* in_sizes, int n_in,
                              void* d_out, int out_size, void* d_ws, size_t ws_size,
                              hipStream_t stream)
{
    const float* xyz1    = (const float*)d_in[0];
    const float* xyz2    = (const float*)d_in[1];
    const float* points1 = (const float*)d_in[2];
    const float* points2 = (const float*)d_in[3];
    const float* w0  = (const float*)d_in[4];
    const float* g0  = (const float*)d_in[6];
    const float* be0 = (const float*)d_in[7];
    const float* w1  = (const float*)d_in[8];
    const float* g1  = (const float*)d_in[10];
    const float* be1 = (const float*)d_in[11];
    float* out = (float*)d_out;
    char* ws = (char*)d_ws;

    bf16* Abf     = (bf16*)(ws);                    // 65536*384*2 = 50,331,648
    bf16* hpre_bf = (bf16*)(ws + 50331648);         // 65536*256*2 = 33,554,432
    bf16* hbf     = (bf16*)(ws + 83886080);         // 65536*256*2 = 33,554,432
    bf16* Wbf0    = (bf16*)(ws + 117440512);        // 256*384*2   =    196,608
    bf16* Wbf1    = (bf16*)(ws + 117637120);        // 128*256*2   =     65,536
    int*  idx3    = (int*) (ws + 117702656);        // 65536*3*4
    float* w3     = (float*)(ws + 118489088);       // 65536*3*4
    float* stats  = (float*)(ws + 119275520);       // 1536*4
    float* sums0 = stats,        *sumsq0 = stats + 256;
    float* sums1 = stats + 512,  *sumsq1 = stats + 640;
    float* scale0 = stats + 768,  *shift0 = stats + 1024;
    float* scale1 = stats + 1280, *shift1 = stats + 1408;

    zero_kernel<<<3, 256, 0, stream>>>(stats, 768);
    cvt_kernel<<<96, 256, 0, stream>>>(w0, Wbf0, H0_ * KA_ / 4);
    cvt_kernel<<<32, 256, 0, stream>>>(w1, Wbf1, H1_ * H0_ / 4);
    p1cvt_kernel<<<R_ * (C1_ / 4) / 256, 256, 0, stream>>>(points1, Abf);
    top3_kernel<<<B_ * (N_ / 64), 256, 0, stream>>>(xyz1, xyz2, idx3, w3);
    interp_kernel<<<R_ / 4, 256, 0, stream>>>(points2, idx3, w3, Abf);

    mfma_gemm_kernel<KA_, H0_, true><<<dim3(R_ / 128, 2), 256, 0, stream>>>(
        Abf, Wbf0, hpre_bf, sums0, sumsq0);
    finalize_kernel<<<1, 256, 0, stream>>>(sums0, sumsq0, g0, be0, scale0, shift0, 1.f / R_);
    bnrelu_cvt_kernel<<<R_ * H0_ / 8 / 256, 256, 0, stream>>>(hpre_bf, scale0, shift0, hbf);

    mfma_gemm_kernel<H0_, H1_, false><<<dim3(R_ / 128, 1), 256, 0, stream>>>(
        hbf, Wbf1, out, sums1, sumsq1);
    finalize_kernel<<<1, 128, 0, stream>>>(sums1, sumsq1, g1, be1, scale1, shift1, 1.f / R_);
    bnrelu_kernel<<<R_ * H1_ / 4 / 256, 256, 0, stream>>>(out, scale1, shift1);
}

// Round 8
// 183.872 us; speedup vs baseline: 1.1257x; 1.1257x over previous
//
#include <hip/hip_runtime.h>

#define B_  8
#define N_  8192
#define S_  2048
#define C1_ 128
#define C2_ 256
#define KA_ 384   // C1_+C2_
#define H0_ 256
#define H1_ 128
#define R_  (B_ * N_)   // 65536

typedef __bf16 bf16;
typedef __attribute__((ext_vector_type(2))) __bf16 bf16x2;
typedef __attribute__((ext_vector_type(4))) __bf16 bf16x4;
typedef __attribute__((ext_vector_type(8))) __bf16 bf16x8;
typedef __attribute__((ext_vector_type(4))) float f32x4;

__device__ __forceinline__ void gload_lds16(const void* g, void* l) {
    __builtin_amdgcn_global_load_lds(
        (const __attribute__((address_space(1))) void*)g,
        (__attribute__((address_space(3))) void*)l, 16, 0, 0);
}

// ---------------- zero stats ----------------
__global__ void zero_kernel(float* __restrict__ p, int n) {
    int i = blockIdx.x * 256 + threadIdx.x;
    if (i < n) p[i] = 0.f;
}

// ---------------- f32 -> bf16 contiguous cast (weights) ----------------
__global__ __launch_bounds__(256) void cvt_kernel(const float* __restrict__ src,
                                                  bf16* __restrict__ dst, int n4) {
    int i = blockIdx.x * 256 + threadIdx.x;
    if (i < n4) {
        float4 v = *(const float4*)(src + (size_t)i * 4);
        bf16x4 o = { (bf16)v.x, (bf16)v.y, (bf16)v.z, (bf16)v.w };
        *(bf16x4*)(dst + (size_t)i * 4) = o;
    }
}

// ---------------- top-3 NN (R5 exact): 1 query/thread, split-4 interleaved ------
// grid: B_ * (N_/64) = 1024 blocks, 256 threads = 64 queries x 4 splits.
// s = 4*i+sp: 4 distinct float4 addrs span banks 0..15 (conflict-free broadcast).
// 1 ds_read_b128 + 3 FMA per pair; rare-taken branchy insert (1 q/thread keeps
// the cheap divergent branch -- do NOT Q-block or flatten, see R4/R6 regressions).
__global__ __launch_bounds__(256) void top3_kernel(
    const float* __restrict__ xyz1, const float* __restrict__ xyz2,
    int* __restrict__ out_idx, float* __restrict__ out_w)
{
    __shared__ float4 sc[S_];          // 32 KB: (x,y,z,|c|^2)
    __shared__ float  md[64][4][3];    // 3 KB
    __shared__ int    mi[64][4][3];    // 3 KB

    int b = blockIdx.x >> 7;           // 128 tiles per batch
    int ntile = blockIdx.x & 127;
    const float* src = xyz2 + (size_t)b * S_ * 3;
    for (int i = threadIdx.x; i < S_; i += 256) {
        float x = src[i * 3 + 0], y = src[i * 3 + 1], z = src[i * 3 + 2];
        float4 c; c.x = x; c.y = y; c.z = z; c.w = x * x + y * y + z * z;
        sc[i] = c;
    }
    __syncthreads();

    const int q  = threadIdx.x >> 2;   // [0,64)
    const int sp = threadIdx.x & 3;    // [0,4)
    const size_t row = (size_t)b * N_ + ntile * 64 + q;
    const float ax = -2.f * xyz1[row * 3 + 0];
    const float ay = -2.f * xyz1[row * 3 + 1];
    const float az = -2.f * xyz1[row * 3 + 2];

    float m0 = 1e30f, m1 = 1e30f, m2 = 1e30f;
    int   j0 = 0, j1 = 0, j2 = 0;

    #pragma unroll 4
    for (int i = 0; i < S_ / 4; ++i) {
        int s = i * 4 + sp;
        float4 c = sc[s];
        float m = fmaf(ax, c.x, fmaf(ay, c.y, fmaf(az, c.z, c.w)));
        if (m < m2) {
            if (m < m1) {
                m2 = m1; j2 = j1;
                if (m < m0) { m1 = m0; j1 = j0; m0 = m; j0 = s; }
                else        { m1 = m;  j1 = s; }
            } else { m2 = m; j2 = s; }
        }
    }
    md[q][sp][0] = m0; md[q][sp][1] = m1; md[q][sp][2] = m2;
    mi[q][sp][0] = j0; mi[q][sp][1] = j1; mi[q][sp][2] = j2;
    __syncthreads();

    if (threadIdx.x < 64) {
        int qq = threadIdx.x;
        float d0 = md[qq][0][0], d1 = md[qq][0][1], d2 = md[qq][0][2];
        int   i0 = mi[qq][0][0], i1 = mi[qq][0][1], i2 = mi[qq][0][2];
        #pragma unroll
        for (int p = 1; p < 4; ++p) {
            #pragma unroll
            for (int j = 0; j < 3; ++j) {
                float d = md[qq][p][j]; int s = mi[qq][p][j];
                bool lt2 = (d < d2) || (d == d2 && s < i2);
                if (lt2) {
                    bool lt1 = (d < d1) || (d == d1 && s < i1);
                    if (lt1) {
                        d2 = d1; i2 = i1;
                        bool lt0 = (d < d0) || (d == d0 && s < i0);
                        if (lt0) { d1 = d0; i1 = i0; d0 = d; i0 = s; }
                        else     { d1 = d;  i1 = s; }
                    } else { d2 = d; i2 = s; }
                }
            }
        }
        size_t orow = (size_t)b * N_ + ntile * 64 + qq;
        float px = xyz1[orow * 3 + 0], py = xyz1[orow * 3 + 1], pz = xyz1[orow * 3 + 2];
        float pp = px * px + py * py + pz * pz;
        float r0 = 1.f / (d0 + pp + 1e-8f);
        float r1 = 1.f / (d1 + pp + 1e-8f);
        float r2 = 1.f / (d2 + pp + 1e-8f);
        float inv = 1.f / (r0 + r1 + r2);
        out_idx[orow * 3 + 0] = i0; out_idx[orow * 3 + 1] = i1; out_idx[orow * 3 + 2] = i2;
        out_w[orow * 3 + 0] = r0 * inv; out_w[orow * 3 + 1] = r1 * inv; out_w[orow * 3 + 2] = r2 * inv;
    }
}

// ---------------- gather + interp + points1 cast -> Abf [R][384] bf16 -----------
__global__ __launch_bounds__(256) void interp_kernel(
    const float* __restrict__ points1, const float* __restrict__ points2,
    const int* __restrict__ idx3, const float* __restrict__ w3,
    bf16* __restrict__ Abf)
{
    int t = threadIdx.x;
    size_t row = (size_t)blockIdx.x * 4 + (t >> 6);
    int lane = t & 63;
    int b = (int)(row >> 13);
    const float* p2 = points2 + (size_t)b * S_ * C2_;
    int ia = idx3[row * 3 + 0], ib = idx3[row * 3 + 1], ic = idx3[row * 3 + 2];
    float wa = w3[row * 3 + 0], wb = w3[row * 3 + 1], wc = w3[row * 3 + 2];
    float4 va = *(const float4*)(p2 + (size_t)ia * C2_ + lane * 4);
    float4 vb = *(const float4*)(p2 + (size_t)ib * C2_ + lane * 4);
    float4 vc = *(const float4*)(p2 + (size_t)ic * C2_ + lane * 4);
    bf16x4 o = { (bf16)(wa * va.x + wb * vb.x + wc * vc.x),
                 (bf16)(wa * va.y + wb * vb.y + wc * vc.y),
                 (bf16)(wa * va.z + wb * vb.z + wc * vc.z),
                 (bf16)(wa * va.w + wb * vb.w + wc * vc.w) };
    *(bf16x4*)(Abf + row * KA_ + C1_ + lane * 4) = o;

    float2 p = *(const float2*)(points1 + row * C1_ + lane * 2);
    bf16x2 po = { (bf16)p.x, (bf16)p.y };
    *(bf16x2*)(Abf + row * KA_ + lane * 2) = po;
}

// ---------------- MFMA bf16 GEMM1 with fused BN-stats epilogue ------------------
template<int K, int OT, bool OUTBF>
__global__ __launch_bounds__(256) void mfma_gemm_kernel(
    const bf16* __restrict__ A, const bf16* __restrict__ Wt, void* __restrict__ Cout,
    float* __restrict__ sums, float* __restrict__ sumsq)
{
    __shared__ bf16 As[128 * 32];
    __shared__ bf16 Bs[128 * 32];
    __shared__ float csum[128], csumsq[128];
    const int tid = threadIdx.x;
    const int lane = tid & 63, wave = tid >> 6;
    const int wr = wave >> 1, wc = wave & 1;
    const int r0 = blockIdx.x * 128, o0 = blockIdx.y * 128;

    f32x4 acc[4][4] = {};

    const int l15 = lane & 15, g = lane >> 4;
    const int slot = g ^ ((l15 >> 1) & 3);
    int a_off[4], b_off[4];
    #pragma unroll
    for (int m = 0; m < 4; ++m) a_off[m] = (wr * 64 + m * 16 + l15) * 32 + slot * 8;
    #pragma unroll
    for (int n = 0; n < 4; ++n) b_off[n] = (wc * 64 + n * 16 + l15) * 32 + slot * 8;

    const int c0 = tid, c1 = tid + 256;
    const int ar0 = c0 >> 2, ar1 = c1 >> 2;
    const int kb0 = ((c0 & 3) ^ ((ar0 >> 1) & 3)) * 8;
    const int kb1 = ((c1 & 3) ^ ((ar1 >> 1) & 3)) * 8;

    if (tid < 128) { csum[tid] = 0.f; csumsq[tid] = 0.f; }

    for (int k0 = 0; k0 < K; k0 += 32) {
        __syncthreads();
        gload_lds16(A  + (size_t)(r0 + ar0) * K + k0 + kb0, &As[c0 * 8]);
        gload_lds16(A  + (size_t)(r0 + ar1) * K + k0 + kb1, &As[c1 * 8]);
        gload_lds16(Wt + (size_t)(o0 + ar0) * K + k0 + kb0, &Bs[c0 * 8]);
        gload_lds16(Wt + (size_t)(o0 + ar1) * K + k0 + kb1, &Bs[c1 * 8]);
        __syncthreads();
        bf16x8 af[4], bfr[4];
        #pragma unroll
        for (int m = 0; m < 4; ++m) af[m]  = *(const bf16x8*)&As[a_off[m]];
        #pragma unroll
        for (int n = 0; n < 4; ++n) bfr[n] = *(const bf16x8*)&Bs[b_off[n]];
        #pragma unroll
        for (int m = 0; m < 4; ++m)
            #pragma unroll
            for (int n = 0; n < 4; ++n)
                acc[m][n] = __builtin_amdgcn_mfma_f32_16x16x32_bf16(af[m], bfr[n], acc[m][n], 0, 0, 0);
    }

    const int crow = r0 + wr * 64 + g * 4;
    const int ccol = o0 + wc * 64 + l15;
    #pragma unroll
    for (int m = 0; m < 4; ++m)
        #pragma unroll
        for (int n = 0; n < 4; ++n)
            #pragma unroll
            for (int j = 0; j < 4; ++j) {
                size_t off = (size_t)(crow + m * 16 + j) * OT + ccol + n * 16;
                if (OUTBF) ((bf16*)Cout)[off] = (bf16)acc[m][n][j];
                else       ((float*)Cout)[off] = acc[m][n][j];
            }

    #pragma unroll
    for (int n = 0; n < 4; ++n) {
        float s = 0.f, q = 0.f;
        #pragma unroll
        for (int m = 0; m < 4; ++m)
            #pragma unroll
            for (int j = 0; j < 4; ++j) {
                float v = acc[m][n][j];
                s += v; q = fmaf(v, v, q);
            }
        int col = wc * 64 + n * 16 + l15;
        atomicAdd(&csum[col], s);
        atomicAdd(&csumsq[col], q);
    }
    __syncthreads();
    if (tid < 128) {
        atomicAdd(&sums[o0 + tid], csum[tid]);
        atomicAdd(&sumsq[o0 + tid], csumsq[tid]);
    }
}

// ---------------- MFMA GEMM2: A = relu(bn(hpre)) fused at A-staging -------------
// Fix vs R7: scale/shift staged into proper float[8] local arrays (two aligned
// float4 loads each) and indexed only with compile-time constants -- no
// cross-local pointer walking (that was the R7 UB bug).
__global__ __launch_bounds__(256) void mfma_gemm2_kernel(
    const bf16* __restrict__ Ahp, const bf16* __restrict__ Wt,
    const float* __restrict__ scale, const float* __restrict__ shift,
    float* __restrict__ Cout, float* __restrict__ sums, float* __restrict__ sumsq)
{
    constexpr int K = H0_, OT = H1_;
    __shared__ bf16 As[128 * 32];
    __shared__ bf16 Bs[128 * 32];
    __shared__ float csum[128], csumsq[128];
    const int tid = threadIdx.x;
    const int lane = tid & 63, wave = tid >> 6;
    const int wr = wave >> 1, wc = wave & 1;
    const int r0 = blockIdx.x * 128, o0 = blockIdx.y * 128;

    f32x4 acc[4][4] = {};

    const int l15 = lane & 15, g = lane >> 4;
    const int slot = g ^ ((l15 >> 1) & 3);
    int a_off[4], b_off[4];
    #pragma unroll
    for (int m = 0; m < 4; ++m) a_off[m] = (wr * 64 + m * 16 + l15) * 32 + slot * 8;
    #pragma unroll
    for (int n = 0; n < 4; ++n) b_off[n] = (wc * 64 + n * 16 + l15) * 32 + slot * 8;

    const int c0 = tid, c1 = tid + 256;
    const int ar0 = c0 >> 2, ar1 = c1 >> 2;
    const int kb0 = ((c0 & 3) ^ ((ar0 >> 1) & 3)) * 8;
    const int kb1 = ((c1 & 3) ^ ((ar1 >> 1) & 3)) * 8;

    if (tid < 128) { csum[tid] = 0.f; csumsq[tid] = 0.f; }

    for (int k0 = 0; k0 < K; k0 += 32) {
        // A: reg-stage with BN+ReLU (scale/shift in proper local arrays)
        bf16x8 va0 = *(const bf16x8*)(Ahp + (size_t)(r0 + ar0) * K + k0 + kb0);
        bf16x8 va1 = *(const bf16x8*)(Ahp + (size_t)(r0 + ar1) * K + k0 + kb1);
        float s0a[8], h0a[8], s1a[8], h1a[8];
        *(float4*)&s0a[0] = *(const float4*)(scale + k0 + kb0);
        *(float4*)&s0a[4] = *(const float4*)(scale + k0 + kb0 + 4);
        *(float4*)&h0a[0] = *(const float4*)(shift + k0 + kb0);
        *(float4*)&h0a[4] = *(const float4*)(shift + k0 + kb0 + 4);
        *(float4*)&s1a[0] = *(const float4*)(scale + k0 + kb1);
        *(float4*)&s1a[4] = *(const float4*)(scale + k0 + kb1 + 4);
        *(float4*)&h1a[0] = *(const float4*)(shift + k0 + kb1);
        *(float4*)&h1a[4] = *(const float4*)(shift + k0 + kb1 + 4);
        bf16x8 ra0, ra1;
        #pragma unroll
        for (int j = 0; j < 8; ++j) {
            float f0 = fmaxf(0.f, fmaf((float)va0[j], s0a[j], h0a[j]));
            float f1 = fmaxf(0.f, fmaf((float)va1[j], s1a[j], h1a[j]));
            ra0[j] = (bf16)f0; ra1[j] = (bf16)f1;
        }
        __syncthreads();                 // previous tile's ds_reads done
        gload_lds16(Wt + (size_t)(o0 + ar0) * K + k0 + kb0, &Bs[c0 * 8]);
        gload_lds16(Wt + (size_t)(o0 + ar1) * K + k0 + kb1, &Bs[c1 * 8]);
        *(bf16x8*)&As[c0 * 8] = ra0;
        *(bf16x8*)&As[c1 * 8] = ra1;
        __syncthreads();                 // drains vmcnt + lgkm
        bf16x8 af[4], bfr[4];
        #pragma unroll
        for (int m = 0; m < 4; ++m) af[m]  = *(const bf16x8*)&As[a_off[m]];
        #pragma unroll
        for (int n = 0; n < 4; ++n) bfr[n] = *(const bf16x8*)&Bs[b_off[n]];
        #pragma unroll
        for (int m = 0; m < 4; ++m)
            #pragma unroll
            for (int n = 0; n < 4; ++n)
                acc[m][n] = __builtin_amdgcn_mfma_f32_16x16x32_bf16(af[m], bfr[n], acc[m][n], 0, 0, 0);
    }

    const int crow = r0 + wr * 64 + g * 4;
    const int ccol = o0 + wc * 64 + l15;
    #pragma unroll
    for (int m = 0; m < 4; ++m)
        #pragma unroll
        for (int n = 0; n < 4; ++n)
            #pragma unroll
            for (int j = 0; j < 4; ++j)
                ((float*)Cout)[(size_t)(crow + m * 16 + j) * OT + ccol + n * 16] = acc[m][n][j];

    #pragma unroll
    for (int n = 0; n < 4; ++n) {
        float s = 0.f, q = 0.f;
        #pragma unroll
        for (int m = 0; m < 4; ++m)
            #pragma unroll
            for (int j = 0; j < 4; ++j) {
                float v = acc[m][n][j];
                s += v; q = fmaf(v, v, q);
            }
        int col = wc * 64 + n * 16 + l15;
        atomicAdd(&csum[col], s);
        atomicAdd(&csumsq[col], q);
    }
    __syncthreads();
    if (tid < 128) {
        atomicAdd(&sums[o0 + tid], csum[tid]);
        atomicAdd(&sumsq[o0 + tid], csumsq[tid]);
    }
}

__global__ void finalize_kernel(const float* __restrict__ sums, const float* __restrict__ sumsq,
                                const float* __restrict__ g, const float* __restrict__ be,
                                float* __restrict__ scale, float* __restrict__ shift, float invR)
{
    int c = threadIdx.x;
    float mean = sums[c] * invR;
    float var = sumsq[c] * invR - mean * mean;
    float s = g[c] * rsqrtf(var + 1e-5f);
    scale[c] = s;
    shift[c] = be[c] - mean * s;
}

// ---------------- final in-place BN+ReLU on d_out (f32) ----------------
__global__ __launch_bounds__(256) void bnrelu_kernel(float* __restrict__ X,
                                                     const float* __restrict__ scale,
                                                     const float* __restrict__ shift)
{
    size_t i = (size_t)blockIdx.x * 256 + threadIdx.x;
    float4 v = *(float4*)(X + i * 4);
    int c = (int)((i * 4) & (H1_ - 1));
    v.x = fmaxf(0.f, v.x * scale[c + 0] + shift[c + 0]);
    v.y = fmaxf(0.f, v.y * scale[c + 1] + shift[c + 1]);
    v.z = fmaxf(0.f, v.z * scale[c + 2] + shift[c + 2]);
    v.w = fmaxf(0.f, v.w * scale[c + 3] + shift[c + 3]);
    *(float4*)(X + i * 4) = v;
}

extern "C" void kernel_launch(void* const* d_in, const int* in_sizes, int n_in,
                              void* d_out, int out_size, void* d_ws, size_t ws_size,
                              hipStream_t stream)
{
    const float* xyz1    = (const float*)d_in[0];
    const float* xyz2    = (const float*)d_in[1];
    const float* points1 = (const float*)d_in[2];
    const float* points2 = (const float*)d_in[3];
    const float* w0  = (const float*)d_in[4];
    const float* g0  = (const float*)d_in[6];
    const float* be0 = (const float*)d_in[7];
    const float* w1  = (const float*)d_in[8];
    const float* g1  = (const float*)d_in[10];
    const float* be1 = (const float*)d_in[11];
    float* out = (float*)d_out;
    char* ws = (char*)d_ws;

    bf16* Abf     = (bf16*)(ws);                    // 65536*384*2
    bf16* hpre_bf = (bf16*)(ws + 50331648);         // 65536*256*2
    bf16* Wbf0    = (bf16*)(ws + 117440512);        // 256*384*2
    bf16* Wbf1    = (bf16*)(ws + 117637120);        // 128*256*2
    int*  idx3    = (int*) (ws + 117702656);        // 65536*3*4
    float* w3     = (float*)(ws + 118489088);       // 65536*3*4
    float* stats  = (float*)(ws + 119275520);       // 1536*4
    float* sums0 = stats,        *sumsq0 = stats + 256;
    float* sums1 = stats + 512,  *sumsq1 = stats + 640;
    float* scale0 = stats + 768,  *shift0 = stats + 1024;
    float* scale1 = stats + 1280, *shift1 = stats + 1408;

    zero_kernel<<<3, 256, 0, stream>>>(stats, 768);
    cvt_kernel<<<96, 256, 0, stream>>>(w0, Wbf0, H0_ * KA_ / 4);
    cvt_kernel<<<32, 256, 0, stream>>>(w1, Wbf1, H1_ * H0_ / 4);
    top3_kernel<<<B_ * (N_ / 64), 256, 0, stream>>>(xyz1, xyz2, idx3, w3);
    interp_kernel<<<R_ / 4, 256, 0, stream>>>(points1, points2, idx3, w3, Abf);

    mfma_gemm_kernel<KA_, H0_, true><<<dim3(R_ / 128, 2), 256, 0, stream>>>(
        Abf, Wbf0, hpre_bf, sums0, sumsq0);
    finalize_kernel<<<1, 256, 0, stream>>>(sums0, sumsq0, g0, be0, scale0, shift0, 1.f / R_);

    mfma_gemm2_kernel<<<dim3(R_ / 128, 1), 256, 0, stream>>>(
        hpre_bf, Wbf1, scale0, shift0, out, sums1, sumsq1);
    finalize_kernel<<<1, 128, 0, stream>>>(sums1, sumsq1, g1, be1, scale1, shift1, 1.f / R_);
    bnrelu_kernel<<<R_ * H1_ / 4 / 256, 256, 0, stream>>>(out, scale1, shift1);
}

// Round 9
// 174.979 us; speedup vs baseline: 1.1829x; 1.0508x over previous
//
#include <hip/hip_runtime.h>

#define B_  8
#define N_  8192
#define S_  2048
#define C1_ 128
#define C2_ 256
#define KA_ 384   // C1_+C2_
#define H0_ 256
#define H1_ 128
#define R_  (B_ * N_)   // 65536

typedef __bf16 bf16;
typedef __attribute__((ext_vector_type(2))) __bf16 bf16x2;
typedef __attribute__((ext_vector_type(4))) __bf16 bf16x4;
typedef __attribute__((ext_vector_type(8))) __bf16 bf16x8;
typedef __attribute__((ext_vector_type(4))) float f32x4;

__device__ __forceinline__ void gload_lds16(const void* g, void* l) {
    __builtin_amdgcn_global_load_lds(
        (const __attribute__((address_space(1))) void*)g,
        (__attribute__((address_space(3))) void*)l, 16, 0, 0);
}

// ---------------- prep: w0 cvt (blk 0..95) | w1 cvt (96..127) | zero stats (128) ----
__global__ __launch_bounds__(256) void prep_kernel(const float* __restrict__ w0,
                                                   const float* __restrict__ w1,
                                                   bf16* __restrict__ Wbf0,
                                                   bf16* __restrict__ Wbf1,
                                                   float* __restrict__ stats)
{
    int blk = blockIdx.x, tid = threadIdx.x;
    if (blk < 96) {
        int i = blk * 256 + tid;                 // [0, 24576) float4 of w0
        float4 v = *(const float4*)(w0 + (size_t)i * 4);
        bf16x4 o = { (bf16)v.x, (bf16)v.y, (bf16)v.z, (bf16)v.w };
        *(bf16x4*)(Wbf0 + (size_t)i * 4) = o;
    } else if (blk < 128) {
        int i = (blk - 96) * 256 + tid;          // [0, 8192) float4 of w1
        float4 v = *(const float4*)(w1 + (size_t)i * 4);
        bf16x4 o = { (bf16)v.x, (bf16)v.y, (bf16)v.z, (bf16)v.w };
        *(bf16x4*)(Wbf1 + (size_t)i * 4) = o;
    } else {
        #pragma unroll
        for (int k = 0; k < 3; ++k) stats[k * 256 + tid] = 0.f;
    }
}

// ---------------- top-3 NN + fused gather/interp + p1 cast ----------------------
// Phase 1 (R5-exact scan): 64 queries x 4 splits, s=4*i+sp, branchy insert.
// Phase 2: merge (tid<64) -> idx/w in LDS. Phase 3: all 4 waves gather points2
// rows + interp + points1 cast for the block's 64 rows -> Abf [R][384] bf16.
__global__ __launch_bounds__(256) void top3_interp_kernel(
    const float* __restrict__ xyz1, const float* __restrict__ xyz2,
    const float* __restrict__ points1, const float* __restrict__ points2,
    bf16* __restrict__ Abf)
{
    __shared__ float4 sc[S_];          // 32 KB: (x,y,z,|c|^2)
    __shared__ float  md[64][4][3];    // 3 KB
    __shared__ int    mi[64][4][3];    // 3 KB
    __shared__ int    sidx[64][3];     // 768 B
    __shared__ float  sw[64][3];       // 768 B

    int b = blockIdx.x >> 7;           // 128 tiles per batch
    int ntile = blockIdx.x & 127;
    const float* src = xyz2 + (size_t)b * S_ * 3;
    for (int i = threadIdx.x; i < S_; i += 256) {
        float x = src[i * 3 + 0], y = src[i * 3 + 1], z = src[i * 3 + 2];
        float4 c; c.x = x; c.y = y; c.z = z; c.w = x * x + y * y + z * z;
        sc[i] = c;
    }
    __syncthreads();

    const int q  = threadIdx.x >> 2;   // [0,64)
    const int sp = threadIdx.x & 3;    // [0,4)
    const size_t row = (size_t)b * N_ + ntile * 64 + q;
    const float ax = -2.f * xyz1[row * 3 + 0];
    const float ay = -2.f * xyz1[row * 3 + 1];
    const float az = -2.f * xyz1[row * 3 + 2];

    float m0 = 1e30f, m1 = 1e30f, m2 = 1e30f;
    int   j0 = 0, j1 = 0, j2 = 0;

    #pragma unroll 4
    for (int i = 0; i < S_ / 4; ++i) {
        int s = i * 4 + sp;
        float4 c = sc[s];
        float m = fmaf(ax, c.x, fmaf(ay, c.y, fmaf(az, c.z, c.w)));
        if (m < m2) {
            if (m < m1) {
                m2 = m1; j2 = j1;
                if (m < m0) { m1 = m0; j1 = j0; m0 = m; j0 = s; }
                else        { m1 = m;  j1 = s; }
            } else { m2 = m; j2 = s; }
        }
    }
    md[q][sp][0] = m0; md[q][sp][1] = m1; md[q][sp][2] = m2;
    mi[q][sp][0] = j0; mi[q][sp][1] = j1; mi[q][sp][2] = j2;
    __syncthreads();

    if (threadIdx.x < 64) {
        int qq = threadIdx.x;
        float d0 = md[qq][0][0], d1 = md[qq][0][1], d2 = md[qq][0][2];
        int   i0 = mi[qq][0][0], i1 = mi[qq][0][1], i2 = mi[qq][0][2];
        #pragma unroll
        for (int p = 1; p < 4; ++p) {
            #pragma unroll
            for (int j = 0; j < 3; ++j) {
                float d = md[qq][p][j]; int s = mi[qq][p][j];
                bool lt2 = (d < d2) || (d == d2 && s < i2);
                if (lt2) {
                    bool lt1 = (d < d1) || (d == d1 && s < i1);
                    if (lt1) {
                        d2 = d1; i2 = i1;
                        bool lt0 = (d < d0) || (d == d0 && s < i0);
                        if (lt0) { d1 = d0; i1 = i0; d0 = d; i0 = s; }
                        else     { d1 = d;  i1 = s; }
                    } else { d2 = d; i2 = s; }
                }
            }
        }
        size_t orow = (size_t)b * N_ + ntile * 64 + qq;
        float px = xyz1[orow * 3 + 0], py = xyz1[orow * 3 + 1], pz = xyz1[orow * 3 + 2];
        float pp = px * px + py * py + pz * pz;
        float r0 = 1.f / (d0 + pp + 1e-8f);
        float r1 = 1.f / (d1 + pp + 1e-8f);
        float r2 = 1.f / (d2 + pp + 1e-8f);
        float inv = 1.f / (r0 + r1 + r2);
        sidx[qq][0] = i0; sidx[qq][1] = i1; sidx[qq][2] = i2;
        sw[qq][0] = r0 * inv; sw[qq][1] = r1 * inv; sw[qq][2] = r2 * inv;
    }
    __syncthreads();

    // Phase 3: gather + interp + p1 cast. Wave wv handles rows wv, wv+4, ...
    const int wv = threadIdx.x >> 6, ln = threadIdx.x & 63;
    const size_t rowbase = (size_t)b * N_ + ntile * 64;
    const float* p2 = points2 + (size_t)b * S_ * C2_;
    for (int r = wv; r < 64; r += 4) {
        size_t orow = rowbase + r;
        int ia = sidx[r][0], ib = sidx[r][1], ic = sidx[r][2];
        float wa = sw[r][0], wb = sw[r][1], wc = sw[r][2];
        float4 va = *(const float4*)(p2 + (size_t)ia * C2_ + ln * 4);
        float4 vb = *(const float4*)(p2 + (size_t)ib * C2_ + ln * 4);
        float4 vc = *(const float4*)(p2 + (size_t)ic * C2_ + ln * 4);
        bf16x4 o = { (bf16)(wa * va.x + wb * vb.x + wc * vc.x),
                     (bf16)(wa * va.y + wb * vb.y + wc * vc.y),
                     (bf16)(wa * va.z + wb * vb.z + wc * vc.z),
                     (bf16)(wa * va.w + wb * vb.w + wc * vc.w) };
        *(bf16x4*)(Abf + orow * KA_ + C1_ + ln * 4) = o;

        float2 p = *(const float2*)(points1 + orow * C1_ + ln * 2);
        bf16x2 po = { (bf16)p.x, (bf16)p.y };
        *(bf16x2*)(Abf + orow * KA_ + ln * 2) = po;
    }
}

// ---------------- MFMA bf16 GEMM1 with fused BN-stats epilogue ------------------
template<int K, int OT, bool OUTBF>
__global__ __launch_bounds__(256) void mfma_gemm_kernel(
    const bf16* __restrict__ A, const bf16* __restrict__ Wt, void* __restrict__ Cout,
    float* __restrict__ sums, float* __restrict__ sumsq)
{
    __shared__ bf16 As[128 * 32];
    __shared__ bf16 Bs[128 * 32];
    __shared__ float csum[128], csumsq[128];
    const int tid = threadIdx.x;
    const int lane = tid & 63, wave = tid >> 6;
    const int wr = wave >> 1, wc = wave & 1;
    const int r0 = blockIdx.x * 128, o0 = blockIdx.y * 128;

    f32x4 acc[4][4] = {};

    const int l15 = lane & 15, g = lane >> 4;
    const int slot = g ^ ((l15 >> 1) & 3);
    int a_off[4], b_off[4];
    #pragma unroll
    for (int m = 0; m < 4; ++m) a_off[m] = (wr * 64 + m * 16 + l15) * 32 + slot * 8;
    #pragma unroll
    for (int n = 0; n < 4; ++n) b_off[n] = (wc * 64 + n * 16 + l15) * 32 + slot * 8;

    const int c0 = tid, c1 = tid + 256;
    const int ar0 = c0 >> 2, ar1 = c1 >> 2;
    const int kb0 = ((c0 & 3) ^ ((ar0 >> 1) & 3)) * 8;
    const int kb1 = ((c1 & 3) ^ ((ar1 >> 1) & 3)) * 8;

    if (tid < 128) { csum[tid] = 0.f; csumsq[tid] = 0.f; }

    for (int k0 = 0; k0 < K; k0 += 32) {
        __syncthreads();
        gload_lds16(A  + (size_t)(r0 + ar0) * K + k0 + kb0, &As[c0 * 8]);
        gload_lds16(A  + (size_t)(r0 + ar1) * K + k0 + kb1, &As[c1 * 8]);
        gload_lds16(Wt + (size_t)(o0 + ar0) * K + k0 + kb0, &Bs[c0 * 8]);
        gload_lds16(Wt + (size_t)(o0 + ar1) * K + k0 + kb1, &Bs[c1 * 8]);
        __syncthreads();
        bf16x8 af[4], bfr[4];
        #pragma unroll
        for (int m = 0; m < 4; ++m) af[m]  = *(const bf16x8*)&As[a_off[m]];
        #pragma unroll
        for (int n = 0; n < 4; ++n) bfr[n] = *(const bf16x8*)&Bs[b_off[n]];
        #pragma unroll
        for (int m = 0; m < 4; ++m)
            #pragma unroll
            for (int n = 0; n < 4; ++n)
                acc[m][n] = __builtin_amdgcn_mfma_f32_16x16x32_bf16(af[m], bfr[n], acc[m][n], 0, 0, 0);
    }

    const int crow = r0 + wr * 64 + g * 4;
    const int ccol = o0 + wc * 64 + l15;
    #pragma unroll
    for (int m = 0; m < 4; ++m)
        #pragma unroll
        for (int n = 0; n < 4; ++n)
            #pragma unroll
            for (int j = 0; j < 4; ++j) {
                size_t off = (size_t)(crow + m * 16 + j) * OT + ccol + n * 16;
                if (OUTBF) ((bf16*)Cout)[off] = (bf16)acc[m][n][j];
                else       ((float*)Cout)[off] = acc[m][n][j];
            }

    #pragma unroll
    for (int n = 0; n < 4; ++n) {
        float s = 0.f, q = 0.f;
        #pragma unroll
        for (int m = 0; m < 4; ++m)
            #pragma unroll
            for (int j = 0; j < 4; ++j) {
                float v = acc[m][n][j];
                s += v; q = fmaf(v, v, q);
            }
        int col = wc * 64 + n * 16 + l15;
        atomicAdd(&csum[col], s);
        atomicAdd(&csumsq[col], q);
    }
    __syncthreads();
    if (tid < 128) {
        atomicAdd(&sums[o0 + tid], csum[tid]);
        atomicAdd(&sumsq[o0 + tid], csumsq[tid]);
    }
}

// ---------------- MFMA GEMM2: inline finalize0 + BN+ReLU fused at A-staging -----
// Prologue computes scale0/shift0 from sums0/sumsq0/g0/be0 into LDS (each block
// redundantly, 256 channels). A reg-staged with BN+ReLU; B via gload_lds;
// epilogue f32 out + fused BN stats1.
__global__ __launch_bounds__(256) void mfma_gemm2_kernel(
    const bf16* __restrict__ Ahp, const bf16* __restrict__ Wt,
    const float* __restrict__ sums0, const float* __restrict__ sumsq0,
    const float* __restrict__ g0, const float* __restrict__ be0,
    float* __restrict__ Cout, float* __restrict__ sums, float* __restrict__ sumsq)
{
    constexpr int K = H0_, OT = H1_;
    __shared__ bf16 As[128 * 32];
    __shared__ bf16 Bs[128 * 32];
    __shared__ float csum[128], csumsq[128];
    __shared__ float sscale[256], sshift[256];
    const int tid = threadIdx.x;
    const int lane = tid & 63, wave = tid >> 6;
    const int wr = wave >> 1, wc = wave & 1;
    const int r0 = blockIdx.x * 128, o0 = blockIdx.y * 128;

    // inline finalize0: channel tid
    {
        const float invR = 1.f / (float)R_;
        float mean = sums0[tid] * invR;
        float var = sumsq0[tid] * invR - mean * mean;
        float sv = g0[tid] * rsqrtf(var + 1e-5f);
        sscale[tid] = sv;
        sshift[tid] = be0[tid] - mean * sv;
    }
    if (tid < 128) { csum[tid] = 0.f; csumsq[tid] = 0.f; }
    __syncthreads();

    f32x4 acc[4][4] = {};

    const int l15 = lane & 15, g = lane >> 4;
    const int slot = g ^ ((l15 >> 1) & 3);
    int a_off[4], b_off[4];
    #pragma unroll
    for (int m = 0; m < 4; ++m) a_off[m] = (wr * 64 + m * 16 + l15) * 32 + slot * 8;
    #pragma unroll
    for (int n = 0; n < 4; ++n) b_off[n] = (wc * 64 + n * 16 + l15) * 32 + slot * 8;

    const int c0 = tid, c1 = tid + 256;
    const int ar0 = c0 >> 2, ar1 = c1 >> 2;
    const int kb0 = ((c0 & 3) ^ ((ar0 >> 1) & 3)) * 8;
    const int kb1 = ((c1 & 3) ^ ((ar1 >> 1) & 3)) * 8;

    for (int k0 = 0; k0 < K; k0 += 32) {
        bf16x8 va0 = *(const bf16x8*)(Ahp + (size_t)(r0 + ar0) * K + k0 + kb0);
        bf16x8 va1 = *(const bf16x8*)(Ahp + (size_t)(r0 + ar1) * K + k0 + kb1);
        float s0a[8], h0a[8], s1a[8], h1a[8];
        *(float4*)&s0a[0] = *(const float4*)(&sscale[k0 + kb0]);
        *(float4*)&s0a[4] = *(const float4*)(&sscale[k0 + kb0 + 4]);
        *(float4*)&h0a[0] = *(const float4*)(&sshift[k0 + kb0]);
        *(float4*)&h0a[4] = *(const float4*)(&sshift[k0 + kb0 + 4]);
        *(float4*)&s1a[0] = *(const float4*)(&sscale[k0 + kb1]);
        *(float4*)&s1a[4] = *(const float4*)(&sscale[k0 + kb1 + 4]);
        *(float4*)&h1a[0] = *(const float4*)(&sshift[k0 + kb1]);
        *(float4*)&h1a[4] = *(const float4*)(&sshift[k0 + kb1 + 4]);
        bf16x8 ra0, ra1;
        #pragma unroll
        for (int j = 0; j < 8; ++j) {
            float f0 = fmaxf(0.f, fmaf((float)va0[j], s0a[j], h0a[j]));
            float f1 = fmaxf(0.f, fmaf((float)va1[j], s1a[j], h1a[j]));
            ra0[j] = (bf16)f0; ra1[j] = (bf16)f1;
        }
        __syncthreads();                 // previous tile's ds_reads done
        gload_lds16(Wt + (size_t)(o0 + ar0) * K + k0 + kb0, &Bs[c0 * 8]);
        gload_lds16(Wt + (size_t)(o0 + ar1) * K + k0 + kb1, &Bs[c1 * 8]);
        *(bf16x8*)&As[c0 * 8] = ra0;
        *(bf16x8*)&As[c1 * 8] = ra1;
        __syncthreads();                 // drains vmcnt + lgkm
        bf16x8 af[4], bfr[4];
        #pragma unroll
        for (int m = 0; m < 4; ++m) af[m]  = *(const bf16x8*)&As[a_off[m]];
        #pragma unroll
        for (int n = 0; n < 4; ++n) bfr[n] = *(const bf16x8*)&Bs[b_off[n]];
        #pragma unroll
        for (int m = 0; m < 4; ++m)
            #pragma unroll
            for (int n = 0; n < 4; ++n)
                acc[m][n] = __builtin_amdgcn_mfma_f32_16x16x32_bf16(af[m], bfr[n], acc[m][n], 0, 0, 0);
    }

    const int crow = r0 + wr * 64 + g * 4;
    const int ccol = o0 + wc * 64 + l15;
    #pragma unroll
    for (int m = 0; m < 4; ++m)
        #pragma unroll
        for (int n = 0; n < 4; ++n)
            #pragma unroll
            for (int j = 0; j < 4; ++j)
                ((float*)Cout)[(size_t)(crow + m * 16 + j) * OT + ccol + n * 16] = acc[m][n][j];

    #pragma unroll
    for (int n = 0; n < 4; ++n) {
        float s = 0.f, q = 0.f;
        #pragma unroll
        for (int m = 0; m < 4; ++m)
            #pragma unroll
            for (int j = 0; j < 4; ++j) {
                float v = acc[m][n][j];
                s += v; q = fmaf(v, v, q);
            }
        int col = wc * 64 + n * 16 + l15;
        atomicAdd(&csum[col], s);
        atomicAdd(&csumsq[col], q);
    }
    __syncthreads();
    if (tid < 128) {
        atomicAdd(&sums[o0 + tid], csum[tid]);
        atomicAdd(&sumsq[o0 + tid], csumsq[tid]);
    }
}

// ---------------- final BN+ReLU on d_out (f32), inline finalize1 ----------------
// 2048 blocks, grid-stride x4. Threads 0..127 compute scale/shift into LDS.
__global__ __launch_bounds__(256) void bnrelu_kernel(
    float* __restrict__ X, const float* __restrict__ sums1,
    const float* __restrict__ sumsq1, const float* __restrict__ g1,
    const float* __restrict__ be1)
{
    __shared__ float ss[128], sh[128];
    int tid = threadIdx.x;
    if (tid < 128) {
        const float invR = 1.f / (float)R_;
        float mean = sums1[tid] * invR;
        float var = sumsq1[tid] * invR - mean * mean;
        float sv = g1[tid] * rsqrtf(var + 1e-5f);
        ss[tid] = sv;
        sh[tid] = be1[tid] - mean * sv;
    }
    __syncthreads();

    #pragma unroll
    for (int it = 0; it < 4; ++it) {
        size_t i = (size_t)it * 524288 + (size_t)blockIdx.x * 256 + tid;  // float4 idx
        int c = ((int)i & 31) * 4;
        float4 v = *(float4*)(X + i * 4);
        v.x = fmaxf(0.f, v.x * ss[c + 0] + sh[c + 0]);
        v.y = fmaxf(0.f, v.y * ss[c + 1] + sh[c + 1]);
        v.z = fmaxf(0.f, v.z * ss[c + 2] + sh[c + 2]);
        v.w = fmaxf(0.f, v.w * ss[c + 3] + sh[c + 3]);
        *(float4*)(X + i * 4) = v;
    }
}

extern "C" void kernel_launch(void* const* d_in, const int* in_sizes, int n_in,
                              void* d_out, int out_size, void* d_ws, size_t ws_size,
                              hipStream_t stream)
{
    const float* xyz1    = (const float*)d_in[0];
    const float* xyz2    = (const float*)d_in[1];
    const float* points1 = (const float*)d_in[2];
    const float* points2 = (const float*)d_in[3];
    const float* w0  = (const float*)d_in[4];
    const float* g0  = (const float*)d_in[6];
    const float* be0 = (const float*)d_in[7];
    const float* w1  = (const float*)d_in[8];
    const float* g1  = (const float*)d_in[10];
    const float* be1 = (const float*)d_in[11];
    float* out = (float*)d_out;
    char* ws = (char*)d_ws;

    bf16* Abf     = (bf16*)(ws);                    // 65536*384*2
    bf16* hpre_bf = (bf16*)(ws + 50331648);         // 65536*256*2
    bf16* Wbf0    = (bf16*)(ws + 117440512);        // 256*384*2
    bf16* Wbf1    = (bf16*)(ws + 117637120);        // 128*256*2
    float* stats  = (float*)(ws + 119275520);       // 768*4
    float* sums0 = stats,        *sumsq0 = stats + 256;
    float* sums1 = stats + 512,  *sumsq1 = stats + 640;

    prep_kernel<<<129, 256, 0, stream>>>(w0, w1, Wbf0, Wbf1, stats);
    top3_interp_kernel<<<B_ * (N_ / 64), 256, 0, stream>>>(xyz1, xyz2, points1, points2, Abf);

    mfma_gemm_kernel<KA_, H0_, true><<<dim3(R_ / 128, 2), 256, 0, stream>>>(
        Abf, Wbf0, hpre_bf, sums0, sumsq0);

    mfma_gemm2_kernel<<<dim3(R_ / 128, 1), 256, 0, stream>>>(
        hpre_bf, Wbf1, sums0, sumsq0, g0, be0, out, sums1, sumsq1);

    bnrelu_kernel<<<2048, 256, 0, stream>>>(out, sums1, sumsq1, g1, be1);
}